// Round 6
// baseline (136.461 us; speedup 1.0000x reference)
//
#include <hip/hip_runtime.h>
#include <hip/hip_bf16.h>
#include <math.h>

#define NB 2
#define CIN 256
#define NPOS 4096          // 64*64
#define HID 128
#define NHEAD 4
#define DHEAD 32
#define NBH 8
#define QSCALE 0.2550348676144781f   // 32^-0.5 * log2(e), folded into W_q rows

typedef __bf16 bf16;
typedef __attribute__((ext_vector_type(8))) __bf16 bf16x8;
typedef __attribute__((ext_vector_type(4))) __bf16 bf16x4;
typedef __attribute__((ext_vector_type(2))) __bf16 bf16x2;
typedef __attribute__((ext_vector_type(4))) float f32x4;

union B8 { bf16x8 v; bf16x4 h[2]; };

// ws layout (byte offsets), total 17,301,504 B (prep/xt/wb/wob removed):
#define QB_OFF  0u            // qb  bf16 [8][4096][32]    2 MB  (pre-scaled by QSCALE via W_q)
#define KB_OFF  2097152u      // kb  bf16 [8][4096][32]    2 MB
#define VT_OFF  4194304u      // vtb bf16 [8][32][4096]    2 MB  (V transposed)
#define AOP_OFF 6291456u      // aop bf16 [4][2][4096][128] 8 MB (partial O, [split][b][i][c])
#define LP_OFF  14680064u     // lp  f32  [4][8][4096]     512 KB
#define AO_OFF  15204352u     // ao  bf16 [2][4096][128]   2 MB  (combine output)

// ---------------- Kernel 1: qkv MFMA GEMM straight from fp32 x / wqkv ----------------
// grid (64 i-tiles, 6 o-tiles, 2 b) = 768 blocks = 3/CU.
// B-stage: x[b][c][i] fp32 -> LDS bf16 [i][c] (transpose+cast in the staging path).
// A-frag: wqkv fp32 rows cast in-register (QSCALE folded for sect==0).
__global__ __launch_bounds__(256) void qkv_kernel(const float* __restrict__ x,
                                                  const float* __restrict__ wqkv,
                                                  bf16* __restrict__ qb,
                                                  bf16* __restrict__ kb,
                                                  bf16* __restrict__ vtb) {
    const int i0 = blockIdx.x * 64;
    const int ot = blockIdx.y * 64;
    const int b  = blockIdx.z;
    const int t  = threadIdx.x;
    const int w  = t >> 6;
    const int lane = t & 63;
    const int quad = lane >> 4;
    const int li   = lane & 15;

    __shared__ bf16 Bs[64][36];   // [i_loc][k], row stride 72 B

    f32x4 acc[4];
    #pragma unroll
    for (int n = 0; n < 4; ++n) acc[n] = (f32x4){0.f, 0.f, 0.f, 0.f};

    // wave-uniform section -> scale for W_q rows
    const int obase = ot + w * 16;
    const int sect  = obase >> 7;            // 0=q 1=k 2=v
    const float wscale = (sect == 0) ? QSCALE : 1.0f;

    const float* xb   = x + (size_t)b * CIN * NPOS + i0;
    const float* wrow = wqkv + (size_t)(obase + li) * CIN;

    const int p  = t & 15;        // c-pair index 0..15 -> c = 2p, 2p+1
    const int ig = t >> 4;        // 0..15 -> i = ig*4 .. +3

    for (int k0 = 0; k0 < CIN; k0 += 32) {
        __syncthreads();
        {
            const float* src = xb + (size_t)(k0 + 2 * p) * NPOS + ig * 4;
            float4 v0 = *(const float4*)src;
            float4 v1 = *(const float4*)(src + NPOS);
            bf16x2 pk;
            pk[0] = (bf16)v0.x; pk[1] = (bf16)v1.x; *(bf16x2*)&Bs[ig * 4 + 0][2 * p] = pk;
            pk[0] = (bf16)v0.y; pk[1] = (bf16)v1.y; *(bf16x2*)&Bs[ig * 4 + 1][2 * p] = pk;
            pk[0] = (bf16)v0.z; pk[1] = (bf16)v1.z; *(bf16x2*)&Bs[ig * 4 + 2][2 * p] = pk;
            pk[0] = (bf16)v0.w; pk[1] = (bf16)v1.w; *(bf16x2*)&Bs[ig * 4 + 3][2 * p] = pk;
        }
        __syncthreads();
        // A-frag: 8 fp32 -> bf16 (scaled)
        float4 a0 = *(const float4*)(wrow + k0 + quad * 8);
        float4 a1 = *(const float4*)(wrow + k0 + quad * 8 + 4);
        B8 af;
        af.v[0] = (bf16)(a0.x * wscale); af.v[1] = (bf16)(a0.y * wscale);
        af.v[2] = (bf16)(a0.z * wscale); af.v[3] = (bf16)(a0.w * wscale);
        af.v[4] = (bf16)(a1.x * wscale); af.v[5] = (bf16)(a1.y * wscale);
        af.v[6] = (bf16)(a1.z * wscale); af.v[7] = (bf16)(a1.w * wscale);
        #pragma unroll
        for (int n = 0; n < 4; ++n) {
            B8 bf;
            bf.h[0] = *(const bf16x4*)&Bs[n * 16 + li][quad * 8];
            bf.h[1] = *(const bf16x4*)&Bs[n * 16 + li][quad * 8 + 4];
            acc[n] = __builtin_amdgcn_mfma_f32_16x16x32_bf16(af.v, bf.v, acc[n], 0, 0, 0);
        }
    }

    const int oo    = obase & 127;
    const int h     = oo >> 5;
    const int dbase = (oo & 31) + quad * 4;
    const int bh    = b * NHEAD + h;

    #pragma unroll
    for (int n = 0; n < 4; ++n) {
        int i = i0 + n * 16 + li;
        f32x4 v = acc[n];
        if (sect <= 1) {
            bf16x4 pk;
            #pragma unroll
            for (int r = 0; r < 4; ++r) pk[r] = (bf16)v[r];
            bf16* base = (sect == 0) ? qb : kb;
            *(bf16x4*)(base + ((size_t)bh * NPOS + i) * DHEAD + dbase) = pk;
        } else {
            #pragma unroll
            for (int r = 0; r < 4; ++r)
                vtb[((size_t)bh * DHEAD + dbase + r) * NPOS + i] = (bf16)v[r];
        }
    }
}

// ---------------- Kernel 2: MFMA flash attention (unchanged from R4/R5) ----------------
__global__ __launch_bounds__(256, 4) void fattn_kernel(const bf16* __restrict__ qb,
                                                       const bf16* __restrict__ kb,
                                                       const bf16* __restrict__ vtb,
                                                       bf16* __restrict__ aop,
                                                       float* __restrict__ lpart) {
    const int id    = blockIdx.x;
    const int g     = id & 31;
    const int iblk  = id >> 5;
    const int bh    = g >> 2;
    const int split = g & 3;
    const int w     = threadIdx.x >> 6;
    const int lane  = threadIdx.x & 63;
    const int quad  = lane >> 4;
    const int li    = lane & 15;
    const int i0    = iblk * 128 + w * 32;
    const int j_lo  = split * 1024;

    const bf16* qrow = qb + (size_t)bh * NPOS * DHEAD;
    const bf16x8 qf0 = *(const bf16x8*)(qrow + (size_t)(i0 + li) * DHEAD + quad * 8);
    const bf16x8 qf1 = *(const bf16x8*)(qrow + (size_t)(i0 + 16 + li) * DHEAD + quad * 8);
    const bf16* kbase  = kb  + (size_t)bh * NPOS * DHEAD;
    const bf16* vtbase = vtb + (size_t)bh * DHEAD * NPOS;

    bf16x8 ones;
    #pragma unroll
    for (int j = 0; j < 8; ++j) ones[j] = (bf16)1.0f;

    f32x4 o00 = {0.f,0.f,0.f,0.f}, o01 = {0.f,0.f,0.f,0.f};
    f32x4 o10 = {0.f,0.f,0.f,0.f}, o11 = {0.f,0.f,0.f,0.f};
    f32x4 l0  = {0.f,0.f,0.f,0.f}, l1  = {0.f,0.f,0.f,0.f};
    __shared__ alignas(16) bf16 plds[4][32][72];

    const f32x4 zero = {0.f,0.f,0.f,0.f};
    for (int jc = j_lo; jc < j_lo + 1024; jc += 256) {
        __syncthreads();   // loose lockstep for L1 stream sharing
        for (int j0 = jc; j0 < jc + 256; j0 += 64) {
            bf16x8 kf[4];
            #pragma unroll
            for (int tt = 0; tt < 4; ++tt)
                kf[tt] = *(const bf16x8*)(kbase + (size_t)(j0 + 16 * tt + li) * DHEAD + quad * 8);
            f32x4 s0[4], s1[4];
            #pragma unroll
            for (int tt = 0; tt < 4; ++tt) {
                s0[tt] = __builtin_amdgcn_mfma_f32_16x16x32_bf16(kf[tt], qf0, zero, 0, 0, 0);
                s1[tt] = __builtin_amdgcn_mfma_f32_16x16x32_bf16(kf[tt], qf1, zero, 0, 0, 0);
            }
            #pragma unroll
            for (int tt = 0; tt < 4; ++tt) {
                bf16x4 p0, p1;
                #pragma unroll
                for (int r = 0; r < 4; ++r) {
                    p0[r] = (bf16)__builtin_exp2f(s0[tt][r]);
                    p1[r] = (bf16)__builtin_exp2f(s1[tt][r]);
                }
                *(bf16x4*)&plds[w][li][16 * tt + quad * 4]      = p0;
                *(bf16x4*)&plds[w][16 + li][16 * tt + quad * 4] = p1;
            }
            #pragma unroll
            for (int h = 0; h < 2; ++h) {
                bf16x8 pf0 = *(const bf16x8*)&plds[w][li][h * 32 + quad * 8];
                bf16x8 pf1 = *(const bf16x8*)&plds[w][16 + li][h * 32 + quad * 8];
                bf16x8 v0f = *(const bf16x8*)(vtbase + (size_t)li        * NPOS + j0 + h * 32 + quad * 8);
                bf16x8 v1f = *(const bf16x8*)(vtbase + (size_t)(16 + li) * NPOS + j0 + h * 32 + quad * 8);
                l0  = __builtin_amdgcn_mfma_f32_16x16x32_bf16(ones, pf0, l0,  0, 0, 0);
                l1  = __builtin_amdgcn_mfma_f32_16x16x32_bf16(ones, pf1, l1,  0, 0, 0);
                o00 = __builtin_amdgcn_mfma_f32_16x16x32_bf16(v0f,  pf0, o00, 0, 0, 0);
                o01 = __builtin_amdgcn_mfma_f32_16x16x32_bf16(v1f,  pf0, o01, 0, 0, 0);
                o10 = __builtin_amdgcn_mfma_f32_16x16x32_bf16(v0f,  pf1, o10, 0, 0, 0);
                o11 = __builtin_amdgcn_mfma_f32_16x16x32_bf16(v1f,  pf1, o11, 0, 0, 0);
            }
        }
    }

    const int b = bh >> 2, h = bh & 3;
    {
        const int i = i0 + li;
        bf16* dst = aop + (((size_t)(split * NB + b) * NPOS + i) * HID) + h * DHEAD;
        bf16x4 pk0, pk1;
        #pragma unroll
        for (int r = 0; r < 4; ++r) { pk0[r] = (bf16)o00[r]; pk1[r] = (bf16)o01[r]; }
        *(bf16x4*)(dst + quad * 4)      = pk0;
        *(bf16x4*)(dst + 16 + quad * 4) = pk1;
        if (quad == 0) lpart[((size_t)split * NBH + bh) * NPOS + i] = l0[0];
    }
    {
        const int i = i0 + 16 + li;
        bf16* dst = aop + (((size_t)(split * NB + b) * NPOS + i) * HID) + h * DHEAD;
        bf16x4 pk0, pk1;
        #pragma unroll
        for (int r = 0; r < 4; ++r) { pk0[r] = (bf16)o10[r]; pk1[r] = (bf16)o11[r]; }
        *(bf16x4*)(dst + quad * 4)      = pk0;
        *(bf16x4*)(dst + 16 + quad * 4) = pk1;
        if (quad == 0) lpart[((size_t)split * NBH + bh) * NPOS + i] = l1[0];
    }
}

// ---------------- Kernel 3: combine splits once: aop + lp -> ao bf16 [b][i][c] ----------------
__global__ __launch_bounds__(256) void combine_kernel(const bf16* __restrict__ aop,
                                                      const float* __restrict__ lpart,
                                                      bf16* __restrict__ ao) {
    const int tid  = blockIdx.x * 256 + threadIdx.x;   // 0..65535
    const int row  = tid >> 3;                         // 0..8191 = b*4096+i
    const int c0   = (tid & 7) * 16;
    const int b    = row >> 12;
    const int i    = row & 4095;
    const int h    = c0 >> 5;

    float lsum = 0.f;
    #pragma unroll
    for (int s = 0; s < 4; ++s)
        lsum += lpart[((size_t)s * NBH + b * NHEAD + h) * NPOS + i];
    const float invl = __builtin_amdgcn_rcpf(lsum);

    float vals[16];
    #pragma unroll
    for (int j = 0; j < 16; ++j) vals[j] = 0.f;
    #pragma unroll
    for (int s = 0; s < 4; ++s) {
        const bf16* src = aop + (((size_t)(s * NB + b) * NPOS + i) * HID) + c0;
        bf16x8 u0 = *(const bf16x8*)src;
        bf16x8 u1 = *(const bf16x8*)(src + 8);
        #pragma unroll
        for (int j = 0; j < 8; ++j) { vals[j] += (float)u0[j]; vals[8 + j] += (float)u1[j]; }
    }
    B8 pk0, pk1;
    #pragma unroll
    for (int j = 0; j < 8; ++j) {
        pk0.v[j] = (bf16)(vals[j] * invl);
        pk1.v[j] = (bf16)(vals[8 + j] * invl);
    }
    bf16* dst = ao + (size_t)row * HID + c0;
    *(bf16x8*)dst       = pk0.v;
    *(bf16x8*)(dst + 8) = pk1.v;
}

// ---------------- Kernel 4: proj bf16 GEMM + bias, wout fp32 cast in-register ----------------
// grid (64 i-tiles, 4 o-tiles, 2 b) = 512 blocks = 2/CU. B-tile staged ONCE (K=128).
__global__ __launch_bounds__(256) void proj_kernel(const bf16* __restrict__ ao,
                                                   const float* __restrict__ wout,
                                                   const float* __restrict__ bout,
                                                   float* __restrict__ y) {
    const int i0 = blockIdx.x * 64;
    const int ot = blockIdx.y * 64;
    const int b  = blockIdx.z;
    const int t  = threadIdx.x;
    const int w  = t >> 6;
    const int lane = t & 63;
    const int quad = lane >> 4;
    const int li   = lane & 15;

    __shared__ bf16 Bs[64][132];   // [i_loc][c]

    {
        const int row = t >> 2;
        const int cp  = (t & 3) * 32;
        const bf16* src = ao + ((size_t)(b * NPOS + i0 + row)) * HID + cp;
        #pragma unroll
        for (int m = 0; m < 4; ++m)
            *(bf16x8*)&Bs[row][cp + m * 8] = *(const bf16x8*)(src + m * 8);
    }
    __syncthreads();

    f32x4 acc[4];
    #pragma unroll
    for (int n = 0; n < 4; ++n) acc[n] = (f32x4){0.f, 0.f, 0.f, 0.f};

    const float* wrow = wout + (size_t)(ot + w * 16 + li) * HID;

    #pragma unroll
    for (int k0 = 0; k0 < HID; k0 += 32) {
        float4 a0 = *(const float4*)(wrow + k0 + quad * 8);
        float4 a1 = *(const float4*)(wrow + k0 + quad * 8 + 4);
        B8 af;
        af.v[0] = (bf16)a0.x; af.v[1] = (bf16)a0.y; af.v[2] = (bf16)a0.z; af.v[3] = (bf16)a0.w;
        af.v[4] = (bf16)a1.x; af.v[5] = (bf16)a1.y; af.v[6] = (bf16)a1.z; af.v[7] = (bf16)a1.w;
        #pragma unroll
        for (int n = 0; n < 4; ++n) {
            B8 bf;
            bf.h[0] = *(const bf16x4*)&Bs[n * 16 + li][k0 + quad * 8];
            bf.h[1] = *(const bf16x4*)&Bs[n * 16 + li][k0 + quad * 8 + 4];
            acc[n] = __builtin_amdgcn_mfma_f32_16x16x32_bf16(af.v, bf.v, acc[n], 0, 0, 0);
        }
    }

    float bias[4];
    #pragma unroll
    for (int r = 0; r < 4; ++r) bias[r] = bout[ot + w * 16 + quad * 4 + r];
    float* yb = y + (size_t)b * CIN * NPOS;
    #pragma unroll
    for (int n = 0; n < 4; ++n) {
        int i = i0 + n * 16 + li;
        #pragma unroll
        for (int r = 0; r < 4; ++r)
            yb[(size_t)(ot + w * 16 + quad * 4 + r) * NPOS + i] = acc[n][r] + bias[r];
    }
}

extern "C" void kernel_launch(void* const* d_in, const int* in_sizes, int n_in,
                              void* d_out, int out_size, void* d_ws, size_t ws_size,
                              hipStream_t stream) {
    const float* x    = (const float*)d_in[0];
    const float* wqkv = (const float*)d_in[1];
    const float* wout = (const float*)d_in[2];
    const float* bout = (const float*)d_in[3];
    float* y = (float*)d_out;
    char* ws = (char*)d_ws;

    bf16*  qb  = (bf16*)(ws + QB_OFF);
    bf16*  kb  = (bf16*)(ws + KB_OFF);
    bf16*  vtb = (bf16*)(ws + VT_OFF);
    bf16*  aop = (bf16*)(ws + AOP_OFF);
    float* lp  = (float*)(ws + LP_OFF);
    bf16*  ao  = (bf16*)(ws + AO_OFF);

    qkv_kernel<<<dim3(64, 6, 2), 256, 0, stream>>>(x, wqkv, qb, kb, vtb);
    fattn_kernel<<<dim3(1024), 256, 0, stream>>>(qb, kb, vtb, aop, lp);
    combine_kernel<<<dim3(256), 256, 0, stream>>>(aop, lp, ao);
    proj_kernel<<<dim3(64, 4, 2), 256, 0, stream>>>(ao, wout, bout, y);
}

// Round 7
// 130.179 us; speedup vs baseline: 1.0483x; 1.0483x over previous
//
#include <hip/hip_runtime.h>
#include <hip/hip_bf16.h>
#include <math.h>

#define NB 2
#define CIN 256
#define NPOS 4096          // 64*64
#define HID 128
#define NHEAD 4
#define DHEAD 32
#define NBH 8
#define QSCALE 0.2550348676144781f   // 32^-0.5 * log2(e), folded into W_q

typedef __bf16 bf16;
typedef __attribute__((ext_vector_type(8))) __bf16 bf16x8;
typedef __attribute__((ext_vector_type(4))) __bf16 bf16x4;
typedef __attribute__((ext_vector_type(4))) float f32x4;

union B8 { bf16x8 v; bf16x4 h[2]; };

// ws layout (byte offsets), total 19,660,800 B (R5 layout):
#define XT_OFF  0u            // xt  bf16 [2][4096][256]   4 MB
#define QB_OFF  4194304u      // qb  bf16 [8][4096][32]    2 MB  (W_q pre-scaled by QSCALE)
#define KB_OFF  6291456u      // kb  bf16 [8][4096][32]    2 MB
#define VT_OFF  8388608u      // vtb bf16 [8][32][4096]    2 MB  (V transposed)
#define AOP_OFF 10485760u     // aop bf16 [4][2][4096][128] 8 MB (partial O, [split][b][i][c])
#define LP_OFF  18874368u     // lp  f32  [4][8][4096]     512 KB
#define WB_OFF  19398656u     // wb  bf16 [384][256]       192 KB
#define WOB_OFF 19595264u     // wob bf16 [256][128]       64 KB

// ---------------- Kernel 0: prep — transpose x to bf16 [b][i][c]; cast weights (R5) ----------------
__global__ __launch_bounds__(256) void prep_kernel(const float* __restrict__ x,
                                                   const float* __restrict__ wqkv,
                                                   const float* __restrict__ wout,
                                                   bf16* __restrict__ xt,
                                                   bf16* __restrict__ wb,
                                                   bf16* __restrict__ wob) {
    const int t = threadIdx.x;
    if (blockIdx.y == 4) {
        int tid = blockIdx.x * 256 + t;           // 0..16383
        if (blockIdx.z == 0) {
            #pragma unroll
            for (int u = 0; u < 6; ++u) {
                int idx = tid * 6 + u;            // 98304 = 384*256 exactly
                float v = wqkv[idx];
                if (idx < 32768) v *= QSCALE;     // rows 0..127 = W_q
                wb[idx] = (bf16)v;
            }
        } else {
            wob[tid * 2]     = (bf16)wout[tid * 2];     // 32768 = 256*128
            wob[tid * 2 + 1] = (bf16)wout[tid * 2 + 1];
        }
        return;
    }
    const int b  = blockIdx.z;
    const int c0 = blockIdx.y * 64;
    const int i0 = blockIdx.x * 64;
    __shared__ float Ts[64][65];
    const float* xb = x + (size_t)b * CIN * NPOS;
    #pragma unroll
    for (int u = 0; u < 4; ++u) {
        int c = (t >> 4) + u * 16;
        int i = (t & 15) * 4;
        float4 v = *(const float4*)(xb + (size_t)(c0 + c) * NPOS + i0 + i);
        Ts[c][i] = v.x; Ts[c][i + 1] = v.y; Ts[c][i + 2] = v.z; Ts[c][i + 3] = v.w;
    }
    __syncthreads();
    int i  = t & 63;
    int cc = (t >> 6) * 16;
    B8 o0, o1;
    #pragma unroll
    for (int j = 0; j < 8; ++j) {
        o0.v[j] = (bf16)Ts[cc + j][i];
        o1.v[j] = (bf16)Ts[cc + 8 + j][i];
    }
    bf16* dst = xt + ((size_t)b * NPOS + i0 + i) * CIN + c0 + cc;
    *(bf16x8*)dst       = o0.v;
    *(bf16x8*)(dst + 8) = o1.v;
}

// ---------------- Kernel 1: qkv MFMA GEMM (R5) ----------------
__global__ __launch_bounds__(256) void qkv_kernel(const bf16* __restrict__ xt,
                                                  const bf16* __restrict__ wb,
                                                  bf16* __restrict__ qb,
                                                  bf16* __restrict__ kb,
                                                  bf16* __restrict__ vtb) {
    const int i0 = blockIdx.x * 64;
    const int ot = blockIdx.y * 64;
    const int b  = blockIdx.z;
    const int t  = threadIdx.x;
    const int w  = t >> 6;
    const int lane = t & 63;
    const int quad = lane >> 4;
    const int li   = lane & 15;

    __shared__ bf16 Bs[64][36];   // [i_loc][k]

    f32x4 acc[4];
    #pragma unroll
    for (int n = 0; n < 4; ++n) acc[n] = (f32x4){0.f, 0.f, 0.f, 0.f};

    const bf16* xrow = xt + ((size_t)b * NPOS + i0) * CIN;
    const int si = t >> 2;            // 0..63
    const int sk = (t & 3) * 8;       // 0,8,16,24

    for (int k0 = 0; k0 < CIN; k0 += 32) {
        __syncthreads();
        B8 g0;
        g0.v = *(const bf16x8*)(xrow + (size_t)si * CIN + k0 + sk);
        *(bf16x4*)&Bs[si][sk]     = g0.h[0];
        *(bf16x4*)&Bs[si][sk + 4] = g0.h[1];
        __syncthreads();
        bf16x8 afrag = *(const bf16x8*)(wb + (size_t)(ot + w * 16 + li) * CIN + k0 + quad * 8);
        #pragma unroll
        for (int n = 0; n < 4; ++n) {
            B8 bf;
            bf.h[0] = *(const bf16x4*)&Bs[n * 16 + li][quad * 8];
            bf.h[1] = *(const bf16x4*)&Bs[n * 16 + li][quad * 8 + 4];
            acc[n] = __builtin_amdgcn_mfma_f32_16x16x32_bf16(afrag, bf.v, acc[n], 0, 0, 0);
        }
    }

    const int obase = ot + w * 16;
    const int sect  = obase >> 7;            // 0=q 1=k 2=v
    const int oo    = obase & 127;
    const int h     = oo >> 5;
    const int dbase = (oo & 31) + quad * 4;
    const int bh    = b * NHEAD + h;

    #pragma unroll
    for (int n = 0; n < 4; ++n) {
        int i = i0 + n * 16 + li;
        f32x4 v = acc[n];
        if (sect <= 1) {
            bf16x4 pk;
            #pragma unroll
            for (int r = 0; r < 4; ++r) pk[r] = (bf16)v[r];
            bf16* base = (sect == 0) ? qb : kb;
            *(bf16x4*)(base + ((size_t)bh * NPOS + i) * DHEAD + dbase) = pk;
        } else {
            #pragma unroll
            for (int r = 0; r < 4; ++r)
                vtb[((size_t)bh * DHEAD + dbase + r) * NPOS + i] = (bf16)v[r];
        }
    }
}

// ---------------- Kernel 2: MFMA flash attention, software-pipelined PV ----------------
// Double-buffered plds: PV of tile t-1 issues between QK-MFMA and exp2 of tile t,
// breaking the per-iteration LDS WAR serialization.
__global__ __launch_bounds__(256, 4) void fattn_kernel(const bf16* __restrict__ qb,
                                                       const bf16* __restrict__ kb,
                                                       const bf16* __restrict__ vtb,
                                                       bf16* __restrict__ aop,
                                                       float* __restrict__ lpart) {
    const int id    = blockIdx.x;
    const int g     = id & 31;
    const int iblk  = id >> 5;
    const int bh    = g >> 2;
    const int split = g & 3;
    const int w     = threadIdx.x >> 6;
    const int lane  = threadIdx.x & 63;
    const int quad  = lane >> 4;
    const int li    = lane & 15;
    const int i0    = iblk * 128 + w * 32;
    const int j_lo  = split * 1024;

    const bf16* qrow = qb + (size_t)bh * NPOS * DHEAD;
    const bf16x8 qf0 = *(const bf16x8*)(qrow + (size_t)(i0 + li) * DHEAD + quad * 8);
    const bf16x8 qf1 = *(const bf16x8*)(qrow + (size_t)(i0 + 16 + li) * DHEAD + quad * 8);
    const bf16* kbase  = kb  + (size_t)bh * NPOS * DHEAD;
    const bf16* vtbase = vtb + (size_t)bh * DHEAD * NPOS;

    bf16x8 ones;
    #pragma unroll
    for (int j = 0; j < 8; ++j) ones[j] = (bf16)1.0f;

    f32x4 o00 = {0.f,0.f,0.f,0.f}, o01 = {0.f,0.f,0.f,0.f};
    f32x4 o10 = {0.f,0.f,0.f,0.f}, o11 = {0.f,0.f,0.f,0.f};
    f32x4 l0  = {0.f,0.f,0.f,0.f}, l1  = {0.f,0.f,0.f,0.f};
    __shared__ alignas(16) bf16 plds[2][4][32][72];   // [buf][wave][i][j], 36 KB

    const f32x4 zero = {0.f,0.f,0.f,0.f};

    auto pv_step = [&](int jp, int pbuf) {
        #pragma unroll
        for (int h2 = 0; h2 < 2; ++h2) {
            bf16x8 pf0 = *(const bf16x8*)&plds[pbuf][w][li][h2 * 32 + quad * 8];
            bf16x8 pf1 = *(const bf16x8*)&plds[pbuf][w][16 + li][h2 * 32 + quad * 8];
            bf16x8 v0f = *(const bf16x8*)(vtbase + (size_t)li        * NPOS + jp + h2 * 32 + quad * 8);
            bf16x8 v1f = *(const bf16x8*)(vtbase + (size_t)(16 + li) * NPOS + jp + h2 * 32 + quad * 8);
            l0  = __builtin_amdgcn_mfma_f32_16x16x32_bf16(ones, pf0, l0,  0, 0, 0);
            l1  = __builtin_amdgcn_mfma_f32_16x16x32_bf16(ones, pf1, l1,  0, 0, 0);
            o00 = __builtin_amdgcn_mfma_f32_16x16x32_bf16(v0f,  pf0, o00, 0, 0, 0);
            o01 = __builtin_amdgcn_mfma_f32_16x16x32_bf16(v1f,  pf0, o01, 0, 0, 0);
            o10 = __builtin_amdgcn_mfma_f32_16x16x32_bf16(v0f,  pf1, o10, 0, 0, 0);
            o11 = __builtin_amdgcn_mfma_f32_16x16x32_bf16(v1f,  pf1, o11, 0, 0, 0);
        }
    };

    for (int it = 0; it < 16; ++it) {
        if ((it & 3) == 0) __syncthreads();   // loose lockstep for L1 stream sharing
        const int j0  = j_lo + it * 64;
        const int buf = it & 1;
        // K loads + QK MFMAs for tile it
        bf16x8 kf[4];
        #pragma unroll
        for (int tt = 0; tt < 4; ++tt)
            kf[tt] = *(const bf16x8*)(kbase + (size_t)(j0 + 16 * tt + li) * DHEAD + quad * 8);
        f32x4 s0[4], s1[4];
        #pragma unroll
        for (int tt = 0; tt < 4; ++tt) {
            s0[tt] = __builtin_amdgcn_mfma_f32_16x16x32_bf16(kf[tt], qf0, zero, 0, 0, 0);
            s1[tt] = __builtin_amdgcn_mfma_f32_16x16x32_bf16(kf[tt], qf1, zero, 0, 0, 0);
        }
        // PV for tile it-1 (independent of s0/s1 — covers QK MFMA latency)
        if (it > 0) pv_step(j_lo + (it - 1) * 64, buf ^ 1);
        // exp + pack + store tile it into plds[buf]
        #pragma unroll
        for (int tt = 0; tt < 4; ++tt) {
            bf16x4 p0, p1;
            #pragma unroll
            for (int r = 0; r < 4; ++r) {
                p0[r] = (bf16)__builtin_exp2f(s0[tt][r]);
                p1[r] = (bf16)__builtin_exp2f(s1[tt][r]);
            }
            *(bf16x4*)&plds[buf][w][li][16 * tt + quad * 4]      = p0;
            *(bf16x4*)&plds[buf][w][16 + li][16 * tt + quad * 4] = p1;
        }
    }
    // drain: PV for the last tile (it=15 stored into buf=1)
    pv_step(j_lo + 15 * 64, 1);

    const int b = bh >> 2, h = bh & 3;
    {
        const int i = i0 + li;
        bf16* dst = aop + (((size_t)(split * NB + b) * NPOS + i) * HID) + h * DHEAD;
        bf16x4 pk0, pk1;
        #pragma unroll
        for (int r = 0; r < 4; ++r) { pk0[r] = (bf16)o00[r]; pk1[r] = (bf16)o01[r]; }
        *(bf16x4*)(dst + quad * 4)      = pk0;
        *(bf16x4*)(dst + 16 + quad * 4) = pk1;
        if (quad == 0) lpart[((size_t)split * NBH + bh) * NPOS + i] = l0[0];
    }
    {
        const int i = i0 + 16 + li;
        bf16* dst = aop + (((size_t)(split * NB + b) * NPOS + i) * HID) + h * DHEAD;
        bf16x4 pk0, pk1;
        #pragma unroll
        for (int r = 0; r < 4; ++r) { pk0[r] = (bf16)o10[r]; pk1[r] = (bf16)o11[r]; }
        *(bf16x4*)(dst + quad * 4)      = pk0;
        *(bf16x4*)(dst + 16 + quad * 4) = pk1;
        if (quad == 0) lpart[((size_t)split * NBH + bh) * NPOS + i] = l1[0];
    }
}

// ---------------- Kernel 3: proj GEMM with fused split-combine in the staging path ----------------
// grid (64 i-tiles, 4 o-tiles, 2 b) = 512 blocks. Staging = combine: sum 4 aop splits,
// scale by 1/l, pack bf16 to LDS once; then K=128 MFMA loop (single barrier).
__global__ __launch_bounds__(256) void proj_kernel(const bf16* __restrict__ aop,
                                                   const float* __restrict__ lpart,
                                                   const bf16* __restrict__ wob,
                                                   const float* __restrict__ bout,
                                                   float* __restrict__ y) {
    const int i0 = blockIdx.x * 64;
    const int ot = blockIdx.y * 64;
    const int b  = blockIdx.z;
    const int t  = threadIdx.x;
    const int w  = t >> 6;
    const int lane = t & 63;
    const int quad = lane >> 4;
    const int li   = lane & 15;

    __shared__ bf16 Bs[64][132];   // [i_loc][c]

    // staging with combine: thread = (row, 32-channel chunk)
    {
        const int row = t >> 2;          // 0..63
        const int cp  = (t & 3) * 32;    // 0,32,64,96 (one head each)
        const int gi  = i0 + row;
        const int h   = cp >> 5;

        float lsum = 0.f;
        #pragma unroll
        for (int s = 0; s < 4; ++s)
            lsum += lpart[((size_t)s * NBH + b * NHEAD + h) * NPOS + gi];
        const float invl = __builtin_amdgcn_rcpf(lsum);

        float vals[32];
        #pragma unroll
        for (int j = 0; j < 32; ++j) vals[j] = 0.f;
        #pragma unroll
        for (int s = 0; s < 4; ++s) {
            const bf16* src = aop + (((size_t)(s * NB + b) * NPOS + gi) * HID) + cp;
            #pragma unroll
            for (int m = 0; m < 4; ++m) {
                bf16x8 u = *(const bf16x8*)(src + m * 8);
                #pragma unroll
                for (int j = 0; j < 8; ++j) vals[m * 8 + j] += (float)u[j];
            }
        }
        #pragma unroll
        for (int m = 0; m < 4; ++m) {
            B8 pk;
            #pragma unroll
            for (int j = 0; j < 8; ++j) pk.v[j] = (bf16)(vals[m * 8 + j] * invl);
            *(bf16x8*)&Bs[row][cp + m * 8] = pk.v;
        }
    }
    __syncthreads();

    f32x4 acc[4];
    #pragma unroll
    for (int n = 0; n < 4; ++n) acc[n] = (f32x4){0.f, 0.f, 0.f, 0.f};

    #pragma unroll
    for (int k0 = 0; k0 < HID; k0 += 32) {
        bf16x8 afrag = *(const bf16x8*)(wob + (size_t)(ot + w * 16 + li) * HID + k0 + quad * 8);
        #pragma unroll
        for (int n = 0; n < 4; ++n) {
            B8 bf;
            bf.h[0] = *(const bf16x4*)&Bs[n * 16 + li][k0 + quad * 8];
            bf.h[1] = *(const bf16x4*)&Bs[n * 16 + li][k0 + quad * 8 + 4];
            acc[n] = __builtin_amdgcn_mfma_f32_16x16x32_bf16(afrag, bf.v, acc[n], 0, 0, 0);
        }
    }

    float bias[4];
    #pragma unroll
    for (int r = 0; r < 4; ++r) bias[r] = bout[ot + w * 16 + quad * 4 + r];
    float* yb = y + (size_t)b * CIN * NPOS;
    #pragma unroll
    for (int n = 0; n < 4; ++n) {
        int i = i0 + n * 16 + li;
        #pragma unroll
        for (int r = 0; r < 4; ++r)
            yb[(size_t)(ot + w * 16 + quad * 4 + r) * NPOS + i] = acc[n][r] + bias[r];
    }
}

extern "C" void kernel_launch(void* const* d_in, const int* in_sizes, int n_in,
                              void* d_out, int out_size, void* d_ws, size_t ws_size,
                              hipStream_t stream) {
    const float* x    = (const float*)d_in[0];
    const float* wqkv = (const float*)d_in[1];
    const float* wout = (const float*)d_in[2];
    const float* bout = (const float*)d_in[3];
    float* y = (float*)d_out;
    char* ws = (char*)d_ws;

    bf16*  xt  = (bf16*)(ws + XT_OFF);
    bf16*  qb  = (bf16*)(ws + QB_OFF);
    bf16*  kb  = (bf16*)(ws + KB_OFF);
    bf16*  vtb = (bf16*)(ws + VT_OFF);
    bf16*  aop = (bf16*)(ws + AOP_OFF);
    float* lp  = (float*)(ws + LP_OFF);
    bf16*  wb  = (bf16*)(ws + WB_OFF);
    bf16*  wob = (bf16*)(ws + WOB_OFF);

    prep_kernel<<<dim3(64, 5, 2), 256, 0, stream>>>(x, wqkv, wout, xt, wb, wob);
    qkv_kernel<<<dim3(64, 6, 2), 256, 0, stream>>>(xt, wb, qb, kb, vtb);
    fattn_kernel<<<dim3(1024), 256, 0, stream>>>(qb, kb, vtb, aop, lp);
    proj_kernel<<<dim3(64, 4, 2), 256, 0, stream>>>(aop, lp, wob, bout, y);
}